// Round 1
// baseline (1716.643 us; speedup 1.0000x reference)
//
#include <hip/hip_runtime.h>
#include <cstddef>

#define B_ 32
#define C_ 32
#define L_ 16384
#define H_ 4
#define DH_ 8
#define NB_ 3
#define DOUT_ 10
#define SEG_ 2048
#define S_ (L_/SEG_)   // 8 segments

__device__ __forceinline__ float gelu_f(float x){
    return 0.5f * x * (1.0f + erff(x * 0.70710678118654752440f));
}

// ---- stats: per (b, head, seg) partial max / sumexp / kv over a 2048-pos segment ----
__global__ __launch_bounds__(256) void stats_kernel(const float* __restrict__ h,
                                                    float* __restrict__ part){
    const int seg = blockIdx.x;
    const int hd  = blockIdx.y;
    const int b   = blockIdx.z;
    const int t   = threadIdx.x;
    const int d   = t >> 5;   // 0..7  (feature within head)
    const int j   = t & 31;   // 0..31 (position lane)

    const float* hb   = h + (size_t)b * ((size_t)C_*L_) + (size_t)(hd*DH_)*L_ + (size_t)seg*SEG_;
    const float* rowd = hb + (size_t)d * L_;

    __shared__ float red[8][32];
    __shared__ float kred[8][8][32];

    // pass 1: per-d max over segment
    float m = -INFINITY;
    for (int k = j; k < SEG_; k += 32) m = fmaxf(m, rowd[k]);
    red[d][j] = m;
    __syncthreads();
    for (int off = 16; off > 0; off >>= 1){
        if (j < off) red[d][j] = fmaxf(red[d][j], red[d][j+off]);
        __syncthreads();
    }
    const float m_d = red[d][0];
    float m_mine = 0.0f;
    if (t < 8) m_mine = red[t][0];
    __syncthreads();

    // pass 2: sumexp + kv partials (unnormalized, referenced to segment max)
    float s = 0.0f;
    float kv[8];
    #pragma unroll
    for (int e = 0; e < 8; e++) kv[e] = 0.0f;
    for (int k = j; k < SEG_; k += 32){
        float ek = __expf(rowd[k] - m_d);
        s += ek;
        #pragma unroll
        for (int e = 0; e < 8; e++) kv[e] += ek * hb[(size_t)e*L_ + k];
    }
    red[d][j] = s;
    #pragma unroll
    for (int e = 0; e < 8; e++) kred[d][e][j] = kv[e];
    __syncthreads();

    float* po = part + (size_t)((b*H_ + hd)*S_ + seg) * 80;
    if (t < 8){
        float ss = 0.0f;
        for (int j2 = 0; j2 < 32; j2++) ss += red[t][j2];
        po[t]     = m_mine;
        po[8 + t] = ss;
    }
    if (t < 64){
        const int dd = t >> 3, ee = t & 7;
        float kk = 0.0f;
        for (int j2 = 0; j2 < 32; j2++) kk += kred[dd][ee][j2];
        po[16 + t] = kk;
    }
}

// ---- merge segment partials -> normalized kvn[b][head][d][e] = kv/s ----
__global__ __launch_bounds__(64) void merge_kernel(const float* __restrict__ part,
                                                   float* __restrict__ kvn){
    const int bh = blockIdx.x;      // 0..B*H-1
    const int t  = threadIdx.x;     // 0..63 -> (d,e)
    const int d  = t >> 3;
    const float* p = part + (size_t)bh * S_ * 80;
    float M = -INFINITY;
    for (int s2 = 0; s2 < S_; s2++) M = fmaxf(M, p[s2*80 + d]);
    float ssum = 0.0f, kvsum = 0.0f;
    for (int s2 = 0; s2 < S_; s2++){
        float sc = __expf(p[s2*80 + d] - M);
        ssum  += p[s2*80 + 8  + d] * sc;
        kvsum += p[s2*80 + 16 + t] * sc;
    }
    kvn[(size_t)bh*64 + t] = kvsum / ssum;
}

// ---- per-position: q-softmax, q@kvn, FC1+gelu, FC2+gelu; write h' or pool ----
template<bool LAST>
__global__ __launch_bounds__(256) void block_kernel(const float* hin,
                                                    float* hout,
                                                    const float* __restrict__ kvn,
                                                    const float* __restrict__ W1,
                                                    const float* __restrict__ b1,
                                                    const float* __restrict__ W2,
                                                    const float* __restrict__ b2,
                                                    float* __restrict__ pooled){
    const int b = blockIdx.y;
    const int l = blockIdx.x * 256 + threadIdx.x;
    const size_t base = (size_t)b * ((size_t)C_*L_);
    const float* kv = kvn + (size_t)b * (H_*DH_*DH_);

    float h[32];
    #pragma unroll
    for (int c = 0; c < 32; c++) h[c] = hin[base + (size_t)c*L_ + l];

    // per-head feature softmax + attn = q @ kvn
    float attn[32];
    #pragma unroll
    for (int hh = 0; hh < 4; hh++){
        float mq = h[hh*8];
        #pragma unroll
        for (int d2 = 1; d2 < 8; d2++) mq = fmaxf(mq, h[hh*8 + d2]);
        float es[8]; float qs = 0.f;
        #pragma unroll
        for (int d2 = 0; d2 < 8; d2++){ es[d2] = __expf(h[hh*8 + d2] - mq); qs += es[d2]; }
        const float inv = 1.0f / qs;
        #pragma unroll
        for (int e = 0; e < 8; e++){
            float a = 0.f;
            #pragma unroll
            for (int d2 = 0; d2 < 8; d2++) a += es[d2] * kv[hh*64 + d2*8 + e];
            attn[hh*8 + e] = a * inv;
        }
    }

    // FC1 + gelu
    float acc[32];
    #pragma unroll
    for (int c = 0; c < 32; c++) acc[c] = b1[c];
    #pragma unroll
    for (int d2 = 0; d2 < 32; d2++){
        const float av = attn[d2];
        #pragma unroll
        for (int c = 0; c < 32; c++) acc[c] += av * W1[d2*32 + c];
    }
    float t1[32];
    #pragma unroll
    for (int c = 0; c < 32; c++) t1[c] = gelu_f(acc[c]);

    // FC2 + gelu
    #pragma unroll
    for (int c = 0; c < 32; c++) acc[c] = b2[c];
    #pragma unroll
    for (int d2 = 0; d2 < 32; d2++){
        const float av = t1[d2];
        #pragma unroll
        for (int c = 0; c < 32; c++) acc[c] += av * W2[d2*32 + c];
    }
    #pragma unroll
    for (int c = 0; c < 32; c++) acc[c] = gelu_f(acc[c]);

    if (!LAST){
        #pragma unroll
        for (int c = 0; c < 32; c++) hout[base + (size_t)c*L_ + l] = acc[c];
    } else {
        __shared__ float pw[4][32];
        const int lane = threadIdx.x & 63;
        const int wave = threadIdx.x >> 6;
        #pragma unroll
        for (int c = 0; c < 32; c++){
            float v = acc[c];
            v += __shfl_xor(v, 32);
            v += __shfl_xor(v, 16);
            v += __shfl_xor(v, 8);
            v += __shfl_xor(v, 4);
            v += __shfl_xor(v, 2);
            v += __shfl_xor(v, 1);
            if (lane == 0) pw[wave][c] = v;
        }
        __syncthreads();
        if (threadIdx.x < 32){
            float v = pw[0][threadIdx.x] + pw[1][threadIdx.x]
                    + pw[2][threadIdx.x] + pw[3][threadIdx.x];
            atomicAdd(&pooled[b*32 + threadIdx.x], v);
        }
    }
}

// ---- head: pooled/L -> Wh+bh -> BN(eval) -> gelu -> Wf+bf ----
__global__ __launch_bounds__(1024) void head_kernel(const float* __restrict__ pooled,
                                                    const float* __restrict__ Wh,
                                                    const float* __restrict__ bh,
                                                    const float* __restrict__ gam,
                                                    const float* __restrict__ bet,
                                                    const float* __restrict__ mean,
                                                    const float* __restrict__ var,
                                                    const float* __restrict__ Wf,
                                                    const float* __restrict__ bf,
                                                    float* __restrict__ out){
    __shared__ float y2[32][32];
    const int t = threadIdx.x;      // 0..1023
    const int b = t >> 5, c = t & 31;
    float a = bh[c];
    const float invL = 1.0f / (float)L_;
    #pragma unroll
    for (int d = 0; d < 32; d++) a += (pooled[b*32 + d] * invL) * Wh[d*32 + c];
    a = (a - mean[c]) * rsqrtf(var[c] + 1e-5f) * gam[c] + bet[c];
    y2[b][c] = gelu_f(a);
    __syncthreads();
    if (t < B_*DOUT_){
        const int b2 = t / DOUT_, j = t % DOUT_;
        float r = bf[j];
        #pragma unroll
        for (int c2 = 0; c2 < 32; c2++) r += y2[b2][c2] * Wf[c2*DOUT_ + j];
        out[t] = r;
    }
}

extern "C" void kernel_launch(void* const* d_in, const int* in_sizes, int n_in,
                              void* d_out, int out_size, void* d_ws, size_t ws_size,
                              hipStream_t stream){
    (void)in_sizes; (void)n_in; (void)out_size; (void)ws_size;
    const float* x    = (const float*)d_in[0];
    const float* fW1  = (const float*)d_in[1];
    const float* fb1  = (const float*)d_in[2];
    const float* fW2  = (const float*)d_in[3];
    const float* fb2  = (const float*)d_in[4];
    const float* Wh   = (const float*)d_in[5];
    const float* bh   = (const float*)d_in[6];
    const float* gam  = (const float*)d_in[7];
    const float* bet  = (const float*)d_in[8];
    const float* mean = (const float*)d_in[9];
    const float* var  = (const float*)d_in[10];
    const float* Wf   = (const float*)d_in[11];
    const float* bf   = (const float*)d_in[12];
    float* out = (float*)d_out;

    float* hbuf   = (float*)d_ws;                          // B*C*L floats (64 MB)
    float* part   = hbuf + (size_t)B_*C_*L_;               // B*H*S*80
    float* kvn    = part + (size_t)B_*H_*S_*80;            // B*H*64
    float* pooled = kvn  + (size_t)B_*H_*64;               // B*C

    hipMemsetAsync(pooled, 0, B_*C_*sizeof(float), stream);

    dim3 sgrid(S_, H_, B_);
    dim3 bgrid(L_/256, B_);

    // block 0 (input = x, output -> hbuf)
    stats_kernel<<<sgrid, 256, 0, stream>>>(x, part);
    merge_kernel<<<B_*H_, 64, 0, stream>>>(part, kvn);
    block_kernel<false><<<bgrid, 256, 0, stream>>>(x, hbuf, kvn, fW1, fb1, fW2, fb2, nullptr);
    // block 1 (in-place on hbuf)
    stats_kernel<<<sgrid, 256, 0, stream>>>(hbuf, part);
    merge_kernel<<<B_*H_, 64, 0, stream>>>(part, kvn);
    block_kernel<false><<<bgrid, 256, 0, stream>>>(hbuf, hbuf, kvn,
        fW1 + C_*C_, fb1 + C_, fW2 + C_*C_, fb2 + C_, nullptr);
    // block 2 (no h write; reduce into pooled)
    stats_kernel<<<sgrid, 256, 0, stream>>>(hbuf, part);
    merge_kernel<<<B_*H_, 64, 0, stream>>>(part, kvn);
    block_kernel<true><<<bgrid, 256, 0, stream>>>(hbuf, nullptr, kvn,
        fW1 + 2*C_*C_, fb1 + 2*C_, fW2 + 2*C_*C_, fb2 + 2*C_, pooled);

    head_kernel<<<1, 1024, 0, stream>>>(pooled, Wh, bh, gam, bet, mean, var, Wf, bf, out);
}

// Round 2
// 961.012 us; speedup vs baseline: 1.7863x; 1.7863x over previous
//
#include <hip/hip_runtime.h>
#include <cstddef>

#define B_ 32
#define C_ 32
#define L_ 16384
#define H_ 4
#define DH_ 8
#define NB_ 3
#define DOUT_ 10
#define SEG_ 2048
#define S_ (L_/SEG_)   // 8 segments

// Branch-free gelu via Abramowitz-Stegun 7.1.26 erf approximation (|eps|<=1.5e-7).
// ~14 VALU ops: 1 v_rcp, 1 v_exp, ~10 fma/mul/add.
__device__ __forceinline__ float gelu_f(float x){
    const float z  = fabsf(x) * 0.70710678118654752440f;
    const float t  = __builtin_amdgcn_rcpf(fmaf(0.3275911f, z, 1.0f));
    const float e  = __expf(-z * z);
    float p = fmaf(t, 1.061405429f, -1.453152027f);
    p = fmaf(t, p, 1.421413741f);
    p = fmaf(t, p, -0.284496736f);
    p = fmaf(t, p, 0.254829592f);
    const float erfz = 1.0f - p * t * e;          // erf(|x|/sqrt(2))
    const float phi  = fmaf(copysignf(erfz, x), 0.5f, 0.5f);
    return x * phi;
}

// ---- stats: per (b, head, seg) partial max / sumexp / kv over a 2048-pos segment ----
__global__ __launch_bounds__(256) void stats_kernel(const float* __restrict__ h,
                                                    float* __restrict__ part){
    const int seg = blockIdx.x;
    const int hd  = blockIdx.y;
    const int b   = blockIdx.z;
    const int t   = threadIdx.x;
    const int d   = t >> 5;   // 0..7  (feature within head)
    const int j   = t & 31;   // 0..31 (position lane)

    const float* hb   = h + (size_t)b * ((size_t)C_*L_) + (size_t)(hd*DH_)*L_ + (size_t)seg*SEG_;
    const float* rowd = hb + (size_t)d * L_;

    __shared__ float red[8][32];
    __shared__ float kred[8][8][32];

    // pass 1: per-d max over segment
    float m = -INFINITY;
    for (int k = j; k < SEG_; k += 32) m = fmaxf(m, rowd[k]);
    red[d][j] = m;
    __syncthreads();
    for (int off = 16; off > 0; off >>= 1){
        if (j < off) red[d][j] = fmaxf(red[d][j], red[d][j+off]);
        __syncthreads();
    }
    const float m_d = red[d][0];
    float m_mine = 0.0f;
    if (t < 8) m_mine = red[t][0];
    __syncthreads();

    // pass 2: sumexp + kv partials (unnormalized, referenced to segment max)
    float s = 0.0f;
    float kv[8];
    #pragma unroll
    for (int e = 0; e < 8; e++) kv[e] = 0.0f;
    for (int k = j; k < SEG_; k += 32){
        float ek = __expf(rowd[k] - m_d);
        s += ek;
        #pragma unroll
        for (int e = 0; e < 8; e++) kv[e] += ek * hb[(size_t)e*L_ + k];
    }
    red[d][j] = s;
    #pragma unroll
    for (int e = 0; e < 8; e++) kred[d][e][j] = kv[e];
    __syncthreads();

    float* po = part + (size_t)((b*H_ + hd)*S_ + seg) * 80;
    if (t < 8){
        float ss = 0.0f;
        for (int j2 = 0; j2 < 32; j2++) ss += red[t][j2];
        po[t]     = m_mine;
        po[8 + t] = ss;
    }
    if (t < 64){
        const int dd = t >> 3, ee = t & 7;
        float kk = 0.0f;
        for (int j2 = 0; j2 < 32; j2++) kk += kred[dd][ee][j2];
        po[16 + t] = kk;
    }
}

// ---- merge segment partials -> normalized kvn[b][head][d][e] = kv/s ----
__global__ __launch_bounds__(64) void merge_kernel(const float* __restrict__ part,
                                                   float* __restrict__ kvn){
    const int bh = blockIdx.x;      // 0..B*H-1
    const int t  = threadIdx.x;     // 0..63 -> (d,e)
    const int d  = t >> 3;
    const float* p = part + (size_t)bh * S_ * 80;
    float M = -INFINITY;
    for (int s2 = 0; s2 < S_; s2++) M = fmaxf(M, p[s2*80 + d]);
    float ssum = 0.0f, kvsum = 0.0f;
    for (int s2 = 0; s2 < S_; s2++){
        float sc = __expf(p[s2*80 + d] - M);
        ssum  += p[s2*80 + 8  + d] * sc;
        kvsum += p[s2*80 + 16 + t] * sc;
    }
    kvn[(size_t)bh*64 + t] = kvsum / ssum;
}

// ---- per-position: q-softmax, q@kvn, FC1+gelu, FC2+gelu; write h' or pool ----
template<bool LAST>
__global__ __launch_bounds__(256) void block_kernel(const float* hin,
                                                    float* hout,
                                                    const float* __restrict__ kvn,
                                                    const float* __restrict__ W1,
                                                    const float* __restrict__ b1,
                                                    const float* __restrict__ W2,
                                                    const float* __restrict__ b2,
                                                    float* __restrict__ pooled){
    const int b = blockIdx.y;
    const int l = blockIdx.x * 256 + threadIdx.x;
    const size_t base = (size_t)b * ((size_t)C_*L_);
    const float* kv = kvn + (size_t)b * (H_*DH_*DH_);

    float h[32];
    #pragma unroll
    for (int c = 0; c < 32; c++) h[c] = hin[base + (size_t)c*L_ + l];

    // per-head feature softmax + attn = q @ kvn
    float attn[32];
    #pragma unroll
    for (int hh = 0; hh < 4; hh++){
        float mq = h[hh*8];
        #pragma unroll
        for (int d2 = 1; d2 < 8; d2++) mq = fmaxf(mq, h[hh*8 + d2]);
        float es[8]; float qs = 0.f;
        #pragma unroll
        for (int d2 = 0; d2 < 8; d2++){ es[d2] = __expf(h[hh*8 + d2] - mq); qs += es[d2]; }
        const float inv = __builtin_amdgcn_rcpf(qs);
        #pragma unroll
        for (int e = 0; e < 8; e++){
            float a = 0.f;
            #pragma unroll
            for (int d2 = 0; d2 < 8; d2++) a += es[d2] * kv[hh*64 + d2*8 + e];
            attn[hh*8 + e] = a * inv;
        }
    }

    // FC1 + gelu
    float acc[32];
    #pragma unroll
    for (int c = 0; c < 32; c++) acc[c] = b1[c];
    #pragma unroll
    for (int d2 = 0; d2 < 32; d2++){
        const float av = attn[d2];
        #pragma unroll
        for (int c = 0; c < 32; c++) acc[c] += av * W1[d2*32 + c];
    }
    float t1[32];
    #pragma unroll
    for (int c = 0; c < 32; c++) t1[c] = gelu_f(acc[c]);

    // FC2 + gelu
    #pragma unroll
    for (int c = 0; c < 32; c++) acc[c] = b2[c];
    #pragma unroll
    for (int d2 = 0; d2 < 32; d2++){
        const float av = t1[d2];
        #pragma unroll
        for (int c = 0; c < 32; c++) acc[c] += av * W2[d2*32 + c];
    }
    #pragma unroll
    for (int c = 0; c < 32; c++) acc[c] = gelu_f(acc[c]);

    if (!LAST){
        #pragma unroll
        for (int c = 0; c < 32; c++) hout[base + (size_t)c*L_ + l] = acc[c];
    } else {
        __shared__ float pw[4][32];
        const int lane = threadIdx.x & 63;
        const int wave = threadIdx.x >> 6;
        #pragma unroll
        for (int c = 0; c < 32; c++){
            float v = acc[c];
            v += __shfl_xor(v, 32);
            v += __shfl_xor(v, 16);
            v += __shfl_xor(v, 8);
            v += __shfl_xor(v, 4);
            v += __shfl_xor(v, 2);
            v += __shfl_xor(v, 1);
            if (lane == 0) pw[wave][c] = v;
        }
        __syncthreads();
        if (threadIdx.x < 32){
            float v = pw[0][threadIdx.x] + pw[1][threadIdx.x]
                    + pw[2][threadIdx.x] + pw[3][threadIdx.x];
            atomicAdd(&pooled[b*32 + threadIdx.x], v);
        }
    }
}

// ---- head: pooled/L -> Wh+bh -> BN(eval) -> gelu -> Wf+bf ----
__global__ __launch_bounds__(1024) void head_kernel(const float* __restrict__ pooled,
                                                    const float* __restrict__ Wh,
                                                    const float* __restrict__ bh,
                                                    const float* __restrict__ gam,
                                                    const float* __restrict__ bet,
                                                    const float* __restrict__ mean,
                                                    const float* __restrict__ var,
                                                    const float* __restrict__ Wf,
                                                    const float* __restrict__ bf,
                                                    float* __restrict__ out){
    __shared__ float y2[32][32];
    const int t = threadIdx.x;      // 0..1023
    const int b = t >> 5, c = t & 31;
    float a = bh[c];
    const float invL = 1.0f / (float)L_;
    #pragma unroll
    for (int d = 0; d < 32; d++) a += (pooled[b*32 + d] * invL) * Wh[d*32 + c];
    a = (a - mean[c]) * rsqrtf(var[c] + 1e-5f) * gam[c] + bet[c];
    y2[b][c] = gelu_f(a);
    __syncthreads();
    if (t < B_*DOUT_){
        const int b2 = t / DOUT_, j = t % DOUT_;
        float r = bf[j];
        #pragma unroll
        for (int c2 = 0; c2 < 32; c2++) r += y2[b2][c2] * Wf[c2*DOUT_ + j];
        out[t] = r;
    }
}

extern "C" void kernel_launch(void* const* d_in, const int* in_sizes, int n_in,
                              void* d_out, int out_size, void* d_ws, size_t ws_size,
                              hipStream_t stream){
    (void)in_sizes; (void)n_in; (void)out_size; (void)ws_size;
    const float* x    = (const float*)d_in[0];
    const float* fW1  = (const float*)d_in[1];
    const float* fb1  = (const float*)d_in[2];
    const float* fW2  = (const float*)d_in[3];
    const float* fb2  = (const float*)d_in[4];
    const float* Wh   = (const float*)d_in[5];
    const float* bh   = (const float*)d_in[6];
    const float* gam  = (const float*)d_in[7];
    const float* bet  = (const float*)d_in[8];
    const float* mean = (const float*)d_in[9];
    const float* var  = (const float*)d_in[10];
    const float* Wf   = (const float*)d_in[11];
    const float* bf   = (const float*)d_in[12];
    float* out = (float*)d_out;

    float* hbuf   = (float*)d_ws;                          // B*C*L floats (64 MB)
    float* part   = hbuf + (size_t)B_*C_*L_;               // B*H*S*80
    float* kvn    = part + (size_t)B_*H_*S_*80;            // B*H*64
    float* pooled = kvn  + (size_t)B_*H_*64;               // B*C

    hipMemsetAsync(pooled, 0, B_*C_*sizeof(float), stream);

    dim3 sgrid(S_, H_, B_);
    dim3 bgrid(L_/256, B_);

    // block 0 (input = x, output -> hbuf)
    stats_kernel<<<sgrid, 256, 0, stream>>>(x, part);
    merge_kernel<<<B_*H_, 64, 0, stream>>>(part, kvn);
    block_kernel<false><<<bgrid, 256, 0, stream>>>(x, hbuf, kvn, fW1, fb1, fW2, fb2, nullptr);
    // block 1 (in-place on hbuf)
    stats_kernel<<<sgrid, 256, 0, stream>>>(hbuf, part);
    merge_kernel<<<B_*H_, 64, 0, stream>>>(part, kvn);
    block_kernel<false><<<bgrid, 256, 0, stream>>>(hbuf, hbuf, kvn,
        fW1 + C_*C_, fb1 + C_, fW2 + C_*C_, fb2 + C_, nullptr);
    // block 2 (no h write; reduce into pooled)
    stats_kernel<<<sgrid, 256, 0, stream>>>(hbuf, part);
    merge_kernel<<<B_*H_, 64, 0, stream>>>(part, kvn);
    block_kernel<true><<<bgrid, 256, 0, stream>>>(hbuf, nullptr, kvn,
        fW1 + 2*C_*C_, fb1 + 2*C_, fW2 + 2*C_*C_, fb2 + 2*C_, pooled);

    head_kernel<<<1, 1024, 0, stream>>>(pooled, Wh, bh, gam, bet, mean, var, Wf, bf, out);
}

// Round 3
// 659.772 us; speedup vs baseline: 2.6019x; 1.4566x over previous
//
#include <hip/hip_runtime.h>
#include <cstddef>

#define B_ 32
#define C_ 32
#define L_ 16384
#define H_ 4
#define DH_ 8
#define NB_ 3
#define DOUT_ 10
#define SEG_ 2048
#define S_ (L_/SEG_)   // 8 segments

// Branch-free gelu via Abramowitz-Stegun 7.1.26 erf approximation (|eps|<=1.5e-7).
__device__ __forceinline__ float gelu_f(float x){
    const float z  = fabsf(x) * 0.70710678118654752440f;
    const float t  = __builtin_amdgcn_rcpf(fmaf(0.3275911f, z, 1.0f));
    const float e  = __expf(-z * z);
    float p = fmaf(t, 1.061405429f, -1.453152027f);
    p = fmaf(t, p, 1.421413741f);
    p = fmaf(t, p, -0.284496736f);
    p = fmaf(t, p, 0.254829592f);
    const float erfz = 1.0f - p * t * e;          // erf(|x|/sqrt(2))
    const float phi  = fmaf(copysignf(erfz, x), 0.5f, 0.5f);
    return x * phi;
}

// ---- stats: per (b, head, seg) partial max / sumexp / kv over a 2048-pos segment ----
__global__ __launch_bounds__(256) void stats_kernel(const float* __restrict__ h,
                                                    float* __restrict__ part){
    const int seg = blockIdx.x;
    const int hd  = blockIdx.y;
    const int b   = blockIdx.z;
    const int t   = threadIdx.x;
    const int d   = t >> 5;   // 0..7  (feature within head)
    const int j   = t & 31;   // 0..31 (position lane)

    const float* hb   = h + (size_t)b * ((size_t)C_*L_) + (size_t)(hd*DH_)*L_ + (size_t)seg*SEG_;
    const float* rowd = hb + (size_t)d * L_;

    __shared__ float red[8][32];
    __shared__ float kred[8][8][32];

    // pass 1: per-d max over segment
    float m = -INFINITY;
    for (int k = j; k < SEG_; k += 32) m = fmaxf(m, rowd[k]);
    red[d][j] = m;
    __syncthreads();
    for (int off = 16; off > 0; off >>= 1){
        if (j < off) red[d][j] = fmaxf(red[d][j], red[d][j+off]);
        __syncthreads();
    }
    const float m_d = red[d][0];
    float m_mine = 0.0f;
    if (t < 8) m_mine = red[t][0];
    __syncthreads();

    // pass 2: sumexp + kv partials (unnormalized, referenced to segment max)
    float s = 0.0f;
    float kv[8];
    #pragma unroll
    for (int e = 0; e < 8; e++) kv[e] = 0.0f;
    for (int k = j; k < SEG_; k += 32){
        float ek = __expf(rowd[k] - m_d);
        s += ek;
        #pragma unroll
        for (int e = 0; e < 8; e++) kv[e] += ek * hb[(size_t)e*L_ + k];
    }
    red[d][j] = s;
    #pragma unroll
    for (int e = 0; e < 8; e++) kred[d][e][j] = kv[e];
    __syncthreads();

    float* po = part + (size_t)((b*H_ + hd)*S_ + seg) * 80;
    if (t < 8){
        float ss = 0.0f;
        for (int j2 = 0; j2 < 32; j2++) ss += red[t][j2];
        po[t]     = m_mine;
        po[8 + t] = ss;
    }
    if (t < 64){
        const int dd = t >> 3, ee = t & 7;
        float kk = 0.0f;
        for (int j2 = 0; j2 < 32; j2++) kk += kred[dd][ee][j2];
        po[16 + t] = kk;
    }
}

// ---- merge segment partials -> normalized kvn[b][head][d][e] = kv/s ----
__global__ __launch_bounds__(64) void merge_kernel(const float* __restrict__ part,
                                                   float* __restrict__ kvn){
    const int bh = blockIdx.x;      // 0..B*H-1
    const int t  = threadIdx.x;     // 0..63 -> (d,e)
    const int d  = t >> 3;
    const float* p = part + (size_t)bh * S_ * 80;
    float M = -INFINITY;
    for (int s2 = 0; s2 < S_; s2++) M = fmaxf(M, p[s2*80 + d]);
    float ssum = 0.0f, kvsum = 0.0f;
    for (int s2 = 0; s2 < S_; s2++){
        float sc = __expf(p[s2*80 + d] - M);
        ssum  += p[s2*80 + 8  + d] * sc;
        kvsum += p[s2*80 + 16 + t] * sc;
    }
    kvn[(size_t)bh*64 + t] = kvsum / ssum;
}

// ---- per-position: q-softmax, q@kvn, FC1+gelu, FC2+gelu; write h' or pool ----
// __launch_bounds__(256, 4): 4 waves/EU -> VGPR budget 128. Without this the
// allocator targets 8 waves/EU (<=64 VGPR) and demotes h/attn/acc/t1 (~100
// live floats) to scratch -> ~5-10x instruction inflation (R2: VGPR=40).
template<bool LAST>
__global__ __launch_bounds__(256, 4) void block_kernel(const float* hin,
                                                    float* hout,
                                                    const float* __restrict__ kvn,
                                                    const float* __restrict__ W1,
                                                    const float* __restrict__ b1,
                                                    const float* __restrict__ W2,
                                                    const float* __restrict__ b2,
                                                    float* __restrict__ pooled){
    const int b = blockIdx.y;
    const int l = blockIdx.x * 256 + threadIdx.x;
    const size_t base = (size_t)b * ((size_t)C_*L_);
    const float* kv = kvn + (size_t)b * (H_*DH_*DH_);

    float h[32];
    #pragma unroll
    for (int c = 0; c < 32; c++) h[c] = hin[base + (size_t)c*L_ + l];

    // per-head feature softmax + attn = q @ kvn
    float attn[32];
    #pragma unroll
    for (int hh = 0; hh < 4; hh++){
        float mq = h[hh*8];
        #pragma unroll
        for (int d2 = 1; d2 < 8; d2++) mq = fmaxf(mq, h[hh*8 + d2]);
        float es[8]; float qs = 0.f;
        #pragma unroll
        for (int d2 = 0; d2 < 8; d2++){ es[d2] = __expf(h[hh*8 + d2] - mq); qs += es[d2]; }
        const float inv = __builtin_amdgcn_rcpf(qs);
        #pragma unroll
        for (int e = 0; e < 8; e++){
            float a = 0.f;
            #pragma unroll
            for (int d2 = 0; d2 < 8; d2++) a += es[d2] * kv[hh*64 + d2*8 + e];
            attn[hh*8 + e] = a * inv;
        }
    }

    // FC1 + gelu
    float acc[32];
    #pragma unroll
    for (int c = 0; c < 32; c++) acc[c] = b1[c];
    #pragma unroll
    for (int d2 = 0; d2 < 32; d2++){
        const float av = attn[d2];
        #pragma unroll
        for (int c = 0; c < 32; c++) acc[c] += av * W1[d2*32 + c];
    }
    float t1[32];
    #pragma unroll
    for (int c = 0; c < 32; c++) t1[c] = gelu_f(acc[c]);

    // FC2 + gelu
    #pragma unroll
    for (int c = 0; c < 32; c++) acc[c] = b2[c];
    #pragma unroll
    for (int d2 = 0; d2 < 32; d2++){
        const float av = t1[d2];
        #pragma unroll
        for (int c = 0; c < 32; c++) acc[c] += av * W2[d2*32 + c];
    }
    #pragma unroll
    for (int c = 0; c < 32; c++) acc[c] = gelu_f(acc[c]);

    if (!LAST){
        #pragma unroll
        for (int c = 0; c < 32; c++) hout[base + (size_t)c*L_ + l] = acc[c];
    } else {
        __shared__ float pw[4][32];
        const int lane = threadIdx.x & 63;
        const int wave = threadIdx.x >> 6;
        #pragma unroll
        for (int c = 0; c < 32; c++){
            float v = acc[c];
            v += __shfl_xor(v, 32);
            v += __shfl_xor(v, 16);
            v += __shfl_xor(v, 8);
            v += __shfl_xor(v, 4);
            v += __shfl_xor(v, 2);
            v += __shfl_xor(v, 1);
            if (lane == 0) pw[wave][c] = v;
        }
        __syncthreads();
        if (threadIdx.x < 32){
            float v = pw[0][threadIdx.x] + pw[1][threadIdx.x]
                    + pw[2][threadIdx.x] + pw[3][threadIdx.x];
            atomicAdd(&pooled[b*32 + threadIdx.x], v);
        }
    }
}

// ---- head: pooled/L -> Wh+bh -> BN(eval) -> gelu -> Wf+bf ----
__global__ __launch_bounds__(1024) void head_kernel(const float* __restrict__ pooled,
                                                    const float* __restrict__ Wh,
                                                    const float* __restrict__ bh,
                                                    const float* __restrict__ gam,
                                                    const float* __restrict__ bet,
                                                    const float* __restrict__ mean,
                                                    const float* __restrict__ var,
                                                    const float* __restrict__ Wf,
                                                    const float* __restrict__ bf,
                                                    float* __restrict__ out){
    __shared__ float y2[32][32];
    const int t = threadIdx.x;      // 0..1023
    const int b = t >> 5, c = t & 31;
    float a = bh[c];
    const float invL = 1.0f / (float)L_;
    #pragma unroll
    for (int d = 0; d < 32; d++) a += (pooled[b*32 + d] * invL) * Wh[d*32 + c];
    a = (a - mean[c]) * rsqrtf(var[c] + 1e-5f) * gam[c] + bet[c];
    y2[b][c] = gelu_f(a);
    __syncthreads();
    if (t < B_*DOUT_){
        const int b2 = t / DOUT_, j = t % DOUT_;
        float r = bf[j];
        #pragma unroll
        for (int c2 = 0; c2 < 32; c2++) r += y2[b2][c2] * Wf[c2*DOUT_ + j];
        out[t] = r;
    }
}

extern "C" void kernel_launch(void* const* d_in, const int* in_sizes, int n_in,
                              void* d_out, int out_size, void* d_ws, size_t ws_size,
                              hipStream_t stream){
    (void)in_sizes; (void)n_in; (void)out_size; (void)ws_size;
    const float* x    = (const float*)d_in[0];
    const float* fW1  = (const float*)d_in[1];
    const float* fb1  = (const float*)d_in[2];
    const float* fW2  = (const float*)d_in[3];
    const float* fb2  = (const float*)d_in[4];
    const float* Wh   = (const float*)d_in[5];
    const float* bh   = (const float*)d_in[6];
    const float* gam  = (const float*)d_in[7];
    const float* bet  = (const float*)d_in[8];
    const float* mean = (const float*)d_in[9];
    const float* var  = (const float*)d_in[10];
    const float* Wf   = (const float*)d_in[11];
    const float* bf   = (const float*)d_in[12];
    float* out = (float*)d_out;

    float* hbuf   = (float*)d_ws;                          // B*C*L floats (64 MB)
    float* part   = hbuf + (size_t)B_*C_*L_;               // B*H*S*80
    float* kvn    = part + (size_t)B_*H_*S_*80;            // B*H*64
    float* pooled = kvn  + (size_t)B_*H_*64;               // B*C

    hipMemsetAsync(pooled, 0, B_*C_*sizeof(float), stream);

    dim3 sgrid(S_, H_, B_);
    dim3 bgrid(L_/256, B_);

    // block 0 (input = x, output -> hbuf)
    stats_kernel<<<sgrid, 256, 0, stream>>>(x, part);
    merge_kernel<<<B_*H_, 64, 0, stream>>>(part, kvn);
    block_kernel<false><<<bgrid, 256, 0, stream>>>(x, hbuf, kvn, fW1, fb1, fW2, fb2, nullptr);
    // block 1 (in-place on hbuf)
    stats_kernel<<<sgrid, 256, 0, stream>>>(hbuf, part);
    merge_kernel<<<B_*H_, 64, 0, stream>>>(part, kvn);
    block_kernel<false><<<bgrid, 256, 0, stream>>>(hbuf, hbuf, kvn,
        fW1 + C_*C_, fb1 + C_, fW2 + C_*C_, fb2 + C_, nullptr);
    // block 2 (no h write; reduce into pooled)
    stats_kernel<<<sgrid, 256, 0, stream>>>(hbuf, part);
    merge_kernel<<<B_*H_, 64, 0, stream>>>(part, kvn);
    block_kernel<true><<<bgrid, 256, 0, stream>>>(hbuf, nullptr, kvn,
        fW1 + 2*C_*C_, fb1 + 2*C_, fW2 + 2*C_*C_, fb2 + 2*C_, pooled);

    head_kernel<<<1, 1024, 0, stream>>>(pooled, Wh, bh, gam, bet, mean, var, Wf, bf, out);
}